// Round 1
// baseline (706.495 us; speedup 1.0000x reference)
//
#include <hip/hip_runtime.h>
#include <hip/hip_bf16.h>

#define N_NODES 100000
#define N_EDGES 1600000
// F == H == 128

typedef short sh8 __attribute__((ext_vector_type(8)));
typedef unsigned short ush8 __attribute__((ext_vector_type(8)));
typedef __bf16 bf8 __attribute__((ext_vector_type(8)));
typedef float f4 __attribute__((ext_vector_type(4)));

__device__ __forceinline__ float lrelu(float v) {
    return v >= 0.0f ? v : 0.01f * v;
}

// f32 -> bf16 (RNE), bit-pattern as ushort
__device__ __forceinline__ unsigned short f2bf(float f) {
    unsigned u = __builtin_bit_cast(unsigned, f);
    return (unsigned short)((u + 0x7FFFu + ((u >> 16) & 1u)) >> 16);
}

// ---------------- CSR build ----------------

__global__ void count_k(const int* __restrict__ dst, int* __restrict__ cnt) {
    int e = blockIdx.x * 256 + threadIdx.x;
    if (e < N_EDGES) atomicAdd(&cnt[dst[e]], 1);
}

// per-chunk inclusive scan (chunk = 1024)
__global__ void scan1(const int* __restrict__ cnt, int* __restrict__ off,
                      int* __restrict__ bsum) {
    __shared__ int lds[1024];
    int t = threadIdx.x;
    int i = blockIdx.x * 1024 + t;
    int v = (i < N_NODES) ? cnt[i] : 0;
    lds[t] = v;
    __syncthreads();
    for (int d = 1; d < 1024; d <<= 1) {
        int add = (t >= d) ? lds[t - d] : 0;
        __syncthreads();
        lds[t] += add;
        __syncthreads();
    }
    if (i < N_NODES) off[i + 1] = lds[t];
    if (t == 1023) bsum[blockIdx.x] = lds[t];
    if (i == 0) off[0] = 0;
}

// exclusive scan of block sums (nb <= 128), single block of 128
__global__ void scan2(int* __restrict__ bsum, int nb) {
    __shared__ int lds[128];
    int t = threadIdx.x;
    int v = (t < nb) ? bsum[t] : 0;
    lds[t] = v;
    __syncthreads();
    for (int d = 1; d < 128; d <<= 1) {
        int add = (t >= d) ? lds[t - d] : 0;
        __syncthreads();
        lds[t] += add;
        __syncthreads();
    }
    if (t < nb) bsum[t] = (t > 0) ? lds[t - 1] : 0;
}

__global__ void scan3(int* __restrict__ off, const int* __restrict__ bsum) {
    int i = blockIdx.x * 1024 + threadIdx.x;
    if (i < N_NODES) off[i + 1] += bsum[blockIdx.x];
}

__global__ void fill_k(const int* __restrict__ src, const int* __restrict__ dst,
                       const int* __restrict__ off, int* __restrict__ cnt,
                       int* __restrict__ csr) {
    int e = blockIdx.x * 256 + threadIdx.x;
    if (e < N_EDGES) {
        int d = dst[e];
        int p = atomicAdd(&cnt[d], 1);
        csr[off[d] + p] = src[e];
    }
}

// ---------------- weights: W -> W^T bf16 ----------------

__global__ void wcast(const float* __restrict__ W1, const float* __restrict__ W2,
                      unsigned short* __restrict__ W1T, unsigned short* __restrict__ W2T) {
    int i = blockIdx.x * 256 + threadIdx.x;
    if (i >= 2 * 16384) return;
    const float* W = (i < 16384) ? W1 : W2;
    unsigned short* T = (i < 16384) ? W1T : W2T;
    int ii = i & 16383;
    int j = ii >> 7, k = ii & 127;   // T[j][k] = W[k][j]
    T[ii] = f2bf(W[k * 128 + j]);
}

// ---------------- fused GEMM: out = lrelu(A @ W + bias (+ res)) ----------------
// A: [N][128] (f32 or bf16), WT: [128][128] bf16 row-major as W^T ([col][k])
template <bool A_F32, bool RES>
__global__ __launch_bounds__(256) void gemm_fused(
    const void* __restrict__ Av, const unsigned short* __restrict__ WT,
    const float* __restrict__ bias, const float* __restrict__ res,
    float* __restrict__ out) {
    __shared__ unsigned short wlds[128][136];  // +8 pad: 272B stride -> 2-way bank alias (free)
    const int tid = threadIdx.x;
#pragma unroll
    for (int it = 0; it < 8; ++it) {
        int idx = it * 256 + tid;
        int r = idx >> 4, c = (idx & 15) << 3;
        *reinterpret_cast<ush8*>(&wlds[r][c]) =
            *reinterpret_cast<const ush8*>(&WT[r * 128 + c]);
    }
    __syncthreads();

    const int lane = tid & 63, wave = tid >> 6;
    const int row0 = blockIdx.x * 64 + wave * 16;
    const int rl = lane & 15, kg = lane >> 4;
    int arow = row0 + rl;
    if (arow >= N_NODES) arow = N_NODES - 1;  // clamp (stores are guarded)

    bf8 af[4];
    if (A_F32) {
        const float* A = (const float*)Av;
#pragma unroll
        for (int kk = 0; kk < 4; ++kk) {
            const float* p = &A[arow * 128 + kk * 32 + kg * 8];
            float4 f0 = *reinterpret_cast<const float4*>(p);
            float4 f1 = *reinterpret_cast<const float4*>(p + 4);
            ush8 v;
            v[0] = f2bf(f0.x); v[1] = f2bf(f0.y); v[2] = f2bf(f0.z); v[3] = f2bf(f0.w);
            v[4] = f2bf(f1.x); v[5] = f2bf(f1.y); v[6] = f2bf(f1.z); v[7] = f2bf(f1.w);
            af[kk] = __builtin_bit_cast(bf8, v);
        }
    } else {
        const unsigned short* A = (const unsigned short*)Av;
#pragma unroll
        for (int kk = 0; kk < 4; ++kk)
            af[kk] = __builtin_bit_cast(
                bf8, *reinterpret_cast<const ush8*>(&A[arow * 128 + kk * 32 + kg * 8]));
    }

    f4 acc[8];
#pragma unroll
    for (int jt = 0; jt < 8; ++jt) acc[jt] = (f4)(0.0f);

#pragma unroll
    for (int jt = 0; jt < 8; ++jt) {
#pragma unroll
        for (int kk = 0; kk < 4; ++kk) {
            bf8 bfr = __builtin_bit_cast(
                bf8, *reinterpret_cast<const ush8*>(&wlds[jt * 16 + rl][kk * 32 + kg * 8]));
            acc[jt] = __builtin_amdgcn_mfma_f32_16x16x32_bf16(af[kk], bfr, acc[jt], 0, 0, 0);
        }
    }

#pragma unroll
    for (int jt = 0; jt < 8; ++jt) {
        int col = jt * 16 + rl;
        float bcol = bias[col];
#pragma unroll
        for (int i = 0; i < 4; ++i) {
            int r = row0 + kg * 4 + i;
            if (r < N_NODES) {
                float v = acc[jt][i] + bcol;
                if (RES) v += res[r * 128 + col];
                out[r * 128 + col] = lrelu(v);
            }
        }
    }
}

// ---------------- aggregation: m[dst] = bf16(mean_{src in N(dst)} h[src]) ----------------
// one wave per dst row, each lane owns 2 floats (float2)
__global__ __launch_bounds__(256) void agg_kernel(
    const float* __restrict__ h, const int* __restrict__ off,
    const int* __restrict__ csr, unsigned short* __restrict__ m) {
    int row = blockIdx.x * 4 + (threadIdx.x >> 6);
    if (row >= N_NODES) return;
    int lane = threadIdx.x & 63;
    int e0 = off[row], e1 = off[row + 1];
    int c = lane * 2;
    float ax = 0.0f, ay = 0.0f;
    int e = e0;
    for (; e + 4 <= e1; e += 4) {
        int s0 = csr[e], s1 = csr[e + 1], s2 = csr[e + 2], s3 = csr[e + 3];
        float2 v0 = *reinterpret_cast<const float2*>(&h[s0 * 128 + c]);
        float2 v1 = *reinterpret_cast<const float2*>(&h[s1 * 128 + c]);
        float2 v2 = *reinterpret_cast<const float2*>(&h[s2 * 128 + c]);
        float2 v3 = *reinterpret_cast<const float2*>(&h[s3 * 128 + c]);
        ax += (v0.x + v1.x) + (v2.x + v3.x);
        ay += (v0.y + v1.y) + (v2.y + v3.y);
    }
    for (; e < e1; ++e) {
        int s = csr[e];
        float2 v = *reinterpret_cast<const float2*>(&h[s * 128 + c]);
        ax += v.x;
        ay += v.y;
    }
    int d = e1 - e0;
    float inv = (d > 0) ? 1.0f / (float)d : 0.0f;
    unsigned pk = ((unsigned)f2bf(ay * inv) << 16) | (unsigned)f2bf(ax * inv);
    *reinterpret_cast<unsigned*>(&m[row * 128 + c]) = pk;
}

// ---------------- launch ----------------

extern "C" void kernel_launch(void* const* d_in, const int* in_sizes, int n_in,
                              void* d_out, int out_size, void* d_ws, size_t ws_size,
                              hipStream_t stream) {
    const float* x  = (const float*)d_in[0];
    const float* W1 = (const float*)d_in[1];
    const float* b1 = (const float*)d_in[2];
    const float* W2 = (const float*)d_in[3];
    const float* b2 = (const float*)d_in[4];
    const int* esrc = (const int*)d_in[5];
    const int* edst = (const int*)d_in[6];
    float* out = (float*)d_out;

    char* ws = (char*)d_ws;
    size_t o = 0;
    auto alloc = [&](size_t b) {
        void* p = ws + o;
        o += (b + 511) & ~(size_t)511;
        return p;
    };
    int* cnt  = (int*)alloc((size_t)N_NODES * 4);
    int* off  = (int*)alloc(((size_t)N_NODES + 1) * 4);
    int* bsum = (int*)alloc(128 * 4);
    int* csr  = (int*)alloc((size_t)N_EDGES * 4);
    unsigned short* W1T = (unsigned short*)alloc(128 * 128 * 2);
    unsigned short* W2T = (unsigned short*)alloc(128 * 128 * 2);
    float* ha = (float*)alloc((size_t)N_NODES * 128 * 4);
    unsigned short* m = (unsigned short*)alloc((size_t)N_NODES * 128 * 2);

    const int NB_SCAN = (N_NODES + 1023) / 1024;  // 98

    hipMemsetAsync(cnt, 0, (size_t)N_NODES * 4, stream);
    count_k<<<(N_EDGES + 255) / 256, 256, 0, stream>>>(edst, cnt);
    scan1<<<NB_SCAN, 1024, 0, stream>>>(cnt, off, bsum);
    scan2<<<1, 128, 0, stream>>>(bsum, NB_SCAN);
    scan3<<<NB_SCAN, 1024, 0, stream>>>(off, bsum);
    hipMemsetAsync(cnt, 0, (size_t)N_NODES * 4, stream);
    fill_k<<<(N_EDGES + 255) / 256, 256, 0, stream>>>(esrc, edst, off, cnt, csr);

    wcast<<<(2 * 16384 + 255) / 256, 256, 0, stream>>>(W1, W2, W1T, W2T);

    const int GB = (N_NODES + 63) / 64;  // 1563
    // fc1: ha = lrelu(x @ W1 + b1)
    gemm_fused<true, false><<<GB, 256, 0, stream>>>(x, W1T, b1, nullptr, ha);

    // 3 iterations, ping-pong so final lands in d_out
    float* hcur = ha;
    float* hnext = out;
    for (int it = 0; it < 3; ++it) {
        agg_kernel<<<(N_NODES + 3) / 4, 256, 0, stream>>>(hcur, off, csr, m);
        gemm_fused<false, true><<<GB, 256, 0, stream>>>(m, W2T, b2, hcur, hnext);
        float* t = hcur; hcur = hnext; hnext = t;
    }
}

// Round 2
// 574.305 us; speedup vs baseline: 1.2302x; 1.2302x over previous
//
#include <hip/hip_runtime.h>
#include <hip/hip_bf16.h>

#define N_NODES 100000
#define N_EDGES 1600000
// F == H == 128

typedef unsigned short ush8 __attribute__((ext_vector_type(8)));
typedef __bf16 bf8 __attribute__((ext_vector_type(8)));
typedef float f4 __attribute__((ext_vector_type(4)));

__device__ __forceinline__ float lrelu(float v) {
    return v >= 0.0f ? v : 0.01f * v;
}

// f32 -> bf16 (RNE), bit-pattern as ushort
__device__ __forceinline__ unsigned short f2bf(float f) {
    unsigned u = __builtin_bit_cast(unsigned, f);
    return (unsigned short)((u + 0x7FFFu + ((u >> 16) & 1u)) >> 16);
}

// ---------------- CSR build ----------------

__global__ void count_k(const int* __restrict__ dst, int* __restrict__ cnt) {
    int e = blockIdx.x * 256 + threadIdx.x;
    if (e < N_EDGES) atomicAdd(&cnt[dst[e]], 1);
}

// per-chunk inclusive scan (chunk = 1024)
__global__ void scan1(const int* __restrict__ cnt, int* __restrict__ off,
                      int* __restrict__ bsum) {
    __shared__ int lds[1024];
    int t = threadIdx.x;
    int i = blockIdx.x * 1024 + t;
    int v = (i < N_NODES) ? cnt[i] : 0;
    lds[t] = v;
    __syncthreads();
    for (int d = 1; d < 1024; d <<= 1) {
        int add = (t >= d) ? lds[t - d] : 0;
        __syncthreads();
        lds[t] += add;
        __syncthreads();
    }
    if (i < N_NODES) off[i + 1] = lds[t];
    if (t == 1023) bsum[blockIdx.x] = lds[t];
    if (i == 0) off[0] = 0;
}

// exclusive scan of block sums (nb <= 128), single block of 128
__global__ void scan2(int* __restrict__ bsum, int nb) {
    __shared__ int lds[128];
    int t = threadIdx.x;
    int v = (t < nb) ? bsum[t] : 0;
    lds[t] = v;
    __syncthreads();
    for (int d = 1; d < 128; d <<= 1) {
        int add = (t >= d) ? lds[t - d] : 0;
        __syncthreads();
        lds[t] += add;
        __syncthreads();
    }
    if (t < nb) bsum[t] = (t > 0) ? lds[t - 1] : 0;
}

__global__ void scan3(int* __restrict__ off, const int* __restrict__ bsum) {
    int i = blockIdx.x * 1024 + threadIdx.x;
    if (i < N_NODES) off[i + 1] += bsum[blockIdx.x];
}

__global__ void fill_k(const int* __restrict__ src, const int* __restrict__ dst,
                       const int* __restrict__ off, int* __restrict__ cnt,
                       int* __restrict__ csr) {
    int e = blockIdx.x * 256 + threadIdx.x;
    if (e < N_EDGES) {
        int d = dst[e];
        int p = atomicAdd(&cnt[d], 1);
        csr[off[d] + p] = src[e];
    }
}

// ---------------- weights: W -> W^T bf16 ----------------

__global__ void wcast(const float* __restrict__ W1, const float* __restrict__ W2,
                      unsigned short* __restrict__ W1T, unsigned short* __restrict__ W2T) {
    int i = blockIdx.x * 256 + threadIdx.x;
    if (i >= 2 * 16384) return;
    const float* W = (i < 16384) ? W1 : W2;
    unsigned short* T = (i < 16384) ? W1T : W2T;
    int ii = i & 16383;
    int j = ii >> 7, k = ii & 127;   // T[j][k] = W[k][j]
    T[ii] = f2bf(W[k * 128 + j]);
}

// ---------------- fused GEMM: out = lrelu(A @ W + bias (+ res)) ----------------
// A: [N][128] (f32 or bf16), WT: [128][128] bf16 row-major as W^T ([col][k])
// Writes f32 out (always) + optional bf16 shadow copy (agg input for next iter).
template <bool A_F32, bool RES, bool WB16>
__global__ __launch_bounds__(256) void gemm_fused(
    const void* __restrict__ Av, const unsigned short* __restrict__ WT,
    const float* __restrict__ bias, const float* __restrict__ res,
    float* __restrict__ outF, unsigned short* __restrict__ outB) {
    __shared__ unsigned short wlds[128][136];  // +8 pad: 272B stride -> 2-way bank alias (free)
    const int tid = threadIdx.x;
#pragma unroll
    for (int it = 0; it < 8; ++it) {
        int idx = it * 256 + tid;
        int r = idx >> 4, c = (idx & 15) << 3;
        *reinterpret_cast<ush8*>(&wlds[r][c]) =
            *reinterpret_cast<const ush8*>(&WT[r * 128 + c]);
    }
    __syncthreads();

    const int lane = tid & 63, wave = tid >> 6;
    const int row0 = blockIdx.x * 64 + wave * 16;
    const int rl = lane & 15, kg = lane >> 4;
    int arow = row0 + rl;
    if (arow >= N_NODES) arow = N_NODES - 1;  // clamp (stores are guarded)

    bf8 af[4];
    if (A_F32) {
        const float* A = (const float*)Av;
#pragma unroll
        for (int kk = 0; kk < 4; ++kk) {
            const float* p = &A[arow * 128 + kk * 32 + kg * 8];
            float4 f0 = *reinterpret_cast<const float4*>(p);
            float4 f1 = *reinterpret_cast<const float4*>(p + 4);
            ush8 v;
            v[0] = f2bf(f0.x); v[1] = f2bf(f0.y); v[2] = f2bf(f0.z); v[3] = f2bf(f0.w);
            v[4] = f2bf(f1.x); v[5] = f2bf(f1.y); v[6] = f2bf(f1.z); v[7] = f2bf(f1.w);
            af[kk] = __builtin_bit_cast(bf8, v);
        }
    } else {
        const unsigned short* A = (const unsigned short*)Av;
#pragma unroll
        for (int kk = 0; kk < 4; ++kk)
            af[kk] = __builtin_bit_cast(
                bf8, *reinterpret_cast<const ush8*>(&A[arow * 128 + kk * 32 + kg * 8]));
    }

    f4 acc[8];
#pragma unroll
    for (int jt = 0; jt < 8; ++jt) acc[jt] = (f4)(0.0f);

#pragma unroll
    for (int jt = 0; jt < 8; ++jt) {
#pragma unroll
        for (int kk = 0; kk < 4; ++kk) {
            bf8 bfr = __builtin_bit_cast(
                bf8, *reinterpret_cast<const ush8*>(&wlds[jt * 16 + rl][kk * 32 + kg * 8]));
            acc[jt] = __builtin_amdgcn_mfma_f32_16x16x32_bf16(af[kk], bfr, acc[jt], 0, 0, 0);
        }
    }

#pragma unroll
    for (int jt = 0; jt < 8; ++jt) {
        int col = jt * 16 + rl;
        float bcol = bias[col];
#pragma unroll
        for (int i = 0; i < 4; ++i) {
            int r = row0 + kg * 4 + i;
            if (r < N_NODES) {
                float v = acc[jt][i] + bcol;
                if (RES) v += res[r * 128 + col];
                v = lrelu(v);
                outF[r * 128 + col] = v;
                if (WB16) outB[r * 128 + col] = f2bf(v);
            }
        }
    }
}

// ---------------- aggregation: m[dst] = bf16(mean_{src in N(dst)} h[src]) ----------------
// h is the bf16 shadow copy. One wave per dst row; lane owns 2 bf16 (one packed u32).
__global__ __launch_bounds__(256) void agg_kernel(
    const unsigned short* __restrict__ h, const int* __restrict__ off,
    const int* __restrict__ csr, unsigned short* __restrict__ m) {
    int row = blockIdx.x * 4 + (threadIdx.x >> 6);
    if (row >= N_NODES) return;
    int lane = threadIdx.x & 63;
    int e0 = off[row], e1 = off[row + 1];
    const unsigned* hb = reinterpret_cast<const unsigned*>(h);  // [N][64] packed bf16x2
    float ax = 0.0f, ay = 0.0f;
    int e = e0;
    for (; e + 8 <= e1; e += 8) {
        int s[8];
#pragma unroll
        for (int k = 0; k < 8; ++k) s[k] = csr[e + k];
#pragma unroll
        for (int k = 0; k < 8; ++k) {
            unsigned u = hb[s[k] * 64 + lane];
            ax += __builtin_bit_cast(float, u << 16);
            ay += __builtin_bit_cast(float, u & 0xFFFF0000u);
        }
    }
    for (; e + 2 <= e1; e += 2) {
        unsigned u0 = hb[csr[e] * 64 + lane];
        unsigned u1 = hb[csr[e + 1] * 64 + lane];
        ax += __builtin_bit_cast(float, u0 << 16) + __builtin_bit_cast(float, u1 << 16);
        ay += __builtin_bit_cast(float, u0 & 0xFFFF0000u) +
              __builtin_bit_cast(float, u1 & 0xFFFF0000u);
    }
    if (e < e1) {
        unsigned u = hb[csr[e] * 64 + lane];
        ax += __builtin_bit_cast(float, u << 16);
        ay += __builtin_bit_cast(float, u & 0xFFFF0000u);
    }
    int d = e1 - e0;
    float inv = (d > 0) ? 1.0f / (float)d : 0.0f;
    unsigned pk = ((unsigned)f2bf(ay * inv) << 16) | (unsigned)f2bf(ax * inv);
    reinterpret_cast<unsigned*>(m)[row * 64 + lane] = pk;
}

// ---------------- launch ----------------

extern "C" void kernel_launch(void* const* d_in, const int* in_sizes, int n_in,
                              void* d_out, int out_size, void* d_ws, size_t ws_size,
                              hipStream_t stream) {
    const float* x  = (const float*)d_in[0];
    const float* W1 = (const float*)d_in[1];
    const float* b1 = (const float*)d_in[2];
    const float* W2 = (const float*)d_in[3];
    const float* b2 = (const float*)d_in[4];
    const int* esrc = (const int*)d_in[5];
    const int* edst = (const int*)d_in[6];
    float* out = (float*)d_out;

    char* ws = (char*)d_ws;
    size_t o = 0;
    auto alloc = [&](size_t b) {
        void* p = ws + o;
        o += (b + 511) & ~(size_t)511;
        return p;
    };
    int* cnt  = (int*)alloc((size_t)N_NODES * 4);
    int* off  = (int*)alloc(((size_t)N_NODES + 1) * 4);
    int* bsum = (int*)alloc(128 * 4);
    int* csr  = (int*)alloc((size_t)N_EDGES * 4);
    unsigned short* W1T = (unsigned short*)alloc(128 * 128 * 2);
    unsigned short* W2T = (unsigned short*)alloc(128 * 128 * 2);
    float* ha = (float*)alloc((size_t)N_NODES * 128 * 4);            // f32 h (residual)
    unsigned short* hB = (unsigned short*)alloc((size_t)N_NODES * 128 * 2);  // bf16 h (agg)
    unsigned short* m  = (unsigned short*)alloc((size_t)N_NODES * 128 * 2);

    const int NB_SCAN = (N_NODES + 1023) / 1024;  // 98

    hipMemsetAsync(cnt, 0, (size_t)N_NODES * 4, stream);
    count_k<<<(N_EDGES + 255) / 256, 256, 0, stream>>>(edst, cnt);
    scan1<<<NB_SCAN, 1024, 0, stream>>>(cnt, off, bsum);
    scan2<<<1, 128, 0, stream>>>(bsum, NB_SCAN);
    scan3<<<NB_SCAN, 1024, 0, stream>>>(off, bsum);
    hipMemsetAsync(cnt, 0, (size_t)N_NODES * 4, stream);
    fill_k<<<(N_EDGES + 255) / 256, 256, 0, stream>>>(esrc, edst, off, cnt, csr);

    wcast<<<(2 * 16384 + 255) / 256, 256, 0, stream>>>(W1, W2, W1T, W2T);

    const int GB = (N_NODES + 63) / 64;  // 1563
    // fc1: h0 = lrelu(x @ W1 + b1)  -> f32 ha + bf16 hB
    gemm_fused<true, false, true><<<GB, 256, 0, stream>>>(x, W1T, b1, nullptr, ha, hB);

    // iter 0: res=ha -> outF=out (+hB)
    agg_kernel<<<(N_NODES + 3) / 4, 256, 0, stream>>>(hB, off, csr, m);
    gemm_fused<false, true, true><<<GB, 256, 0, stream>>>(m, W2T, b2, ha, out, hB);
    // iter 1: res=out -> outF=ha (+hB)
    agg_kernel<<<(N_NODES + 3) / 4, 256, 0, stream>>>(hB, off, csr, m);
    gemm_fused<false, true, true><<<GB, 256, 0, stream>>>(m, W2T, b2, out, ha, hB);
    // iter 2 (final): res=ha -> outF=out (d_out), no bf16 store
    agg_kernel<<<(N_NODES + 3) / 4, 256, 0, stream>>>(hB, off, csr, m);
    gemm_fused<false, true, false><<<GB, 256, 0, stream>>>(m, W2T, b2, ha, out, nullptr);
}

// Round 3
// 487.736 us; speedup vs baseline: 1.4485x; 1.1775x over previous
//
#include <hip/hip_runtime.h>
#include <hip/hip_bf16.h>

#define N_NODES 100000
#define N_EDGES 1600000
// F == H == 128

#define BK_SHIFT 9
#define BK_NODES 512
#define NBKT 196              // ceil(N_NODES / 512)
#define EDGES_PER_BLK 8192
#define NBLK_EDGE ((N_EDGES + EDGES_PER_BLK - 1) / EDGES_PER_BLK)  // 196

typedef unsigned short ush8 __attribute__((ext_vector_type(8)));
typedef __bf16 bf8 __attribute__((ext_vector_type(8)));
typedef float f4 __attribute__((ext_vector_type(4)));

__device__ __forceinline__ float lrelu(float v) {
    return v >= 0.0f ? v : 0.01f * v;
}

// f32 -> bf16 (RNE), bit-pattern as ushort
__device__ __forceinline__ unsigned short f2bf(float f) {
    unsigned u = __builtin_bit_cast(unsigned, f);
    return (unsigned short)((u + 0x7FFFu + ((u >> 16) & 1u)) >> 16);
}

// ---------------- CSR build (bucketed counting sort, dense writes) ----------------

__global__ __launch_bounds__(256) void bucket_count(const int* __restrict__ dst,
                                                    int* __restrict__ bcnt) {
    __shared__ int h[NBKT];
    int t = threadIdx.x;
    for (int i = t; i < NBKT; i += 256) h[i] = 0;
    __syncthreads();
    int base = blockIdx.x * EDGES_PER_BLK;
#pragma unroll 4
    for (int k = 0; k < EDGES_PER_BLK / 256; ++k) {
        int e = base + k * 256 + t;
        if (e < N_EDGES) atomicAdd(&h[dst[e] >> BK_SHIFT], 1);
    }
    __syncthreads();
    for (int i = t; i < NBKT; i += 256)
        if (h[i]) atomicAdd(&bcnt[i], h[i]);
}

// single block: exclusive scan of bucket counts -> boff/bcur; boff[NBKT]=E, off[N]=E
__global__ void scan_buckets(const int* __restrict__ bcnt, int* __restrict__ boff,
                             int* __restrict__ bcur, int* __restrict__ off) {
    __shared__ int lds[256];
    int t = threadIdx.x;
    int v = (t < NBKT) ? bcnt[t] : 0;
    lds[t] = v;
    __syncthreads();
    for (int d = 1; d < 256; d <<= 1) {
        int a = (t >= d) ? lds[t - d] : 0;
        __syncthreads();
        lds[t] += a;
        __syncthreads();
    }
    if (t < NBKT) {
        int excl = lds[t] - v;
        boff[t] = excl;
        bcur[t] = excl;
    }
    if (t == 0) {
        boff[NBKT] = N_EDGES;
        off[N_NODES] = N_EDGES;
    }
}

// scatter edges into bucket-grouped array, packed (src<<9)|dst_local
__global__ __launch_bounds__(256) void bucket_scatter(const int* __restrict__ src,
                                                      const int* __restrict__ dst,
                                                      int* __restrict__ bcur,
                                                      unsigned* __restrict__ binned) {
    __shared__ int h[NBKT];
    __shared__ int bbase[NBKT];
    int t = threadIdx.x;
    for (int i = t; i < NBKT; i += 256) h[i] = 0;
    __syncthreads();
    int base = blockIdx.x * EDGES_PER_BLK;
#pragma unroll 4
    for (int k = 0; k < EDGES_PER_BLK / 256; ++k) {
        int e = base + k * 256 + t;
        if (e < N_EDGES) atomicAdd(&h[dst[e] >> BK_SHIFT], 1);
    }
    __syncthreads();
    for (int i = t; i < NBKT; i += 256) {
        int c = h[i];
        bbase[i] = c ? atomicAdd(&bcur[i], c) : 0;
        h[i] = 0;  // reuse as local cursor
    }
    __syncthreads();
#pragma unroll 4
    for (int k = 0; k < EDGES_PER_BLK / 256; ++k) {
        int e = base + k * 256 + t;
        if (e < N_EDGES) {
            int d = dst[e], s = src[e];
            int b = d >> BK_SHIFT;
            int p = bbase[b] + atomicAdd(&h[b], 1);
            binned[p] = ((unsigned)s << BK_SHIFT) | (unsigned)(d & (BK_NODES - 1));
        }
    }
}

// one block per bucket: local histogram -> scan -> write off[] -> place csr
__global__ __launch_bounds__(256) void bucket_place(const unsigned* __restrict__ binned,
                                                    const int* __restrict__ boff,
                                                    int* __restrict__ off,
                                                    int* __restrict__ csr) {
    __shared__ int hist[BK_NODES];
    __shared__ int pair[256];
    int b = blockIdx.x, t = threadIdx.x;
    int e0 = boff[b], e1 = boff[b + 1];
    hist[t] = 0;
    hist[t + 256] = 0;
    __syncthreads();
    for (int e = e0 + t; e < e1; e += 256)
        atomicAdd(&hist[binned[e] & (BK_NODES - 1)], 1);
    __syncthreads();
    int h0 = hist[2 * t], h1 = hist[2 * t + 1];
    pair[t] = h0 + h1;
    __syncthreads();
    for (int d = 1; d < 256; d <<= 1) {
        int a = (t >= d) ? pair[t - d] : 0;
        __syncthreads();
        pair[t] += a;
        __syncthreads();
    }
    int ep = pair[t] - (h0 + h1);  // exclusive prefix of this pair
    int ex0 = ep, ex1 = ep + h0;
    int node0 = b * BK_NODES + 2 * t;
    if (node0 < N_NODES) off[node0] = e0 + ex0;
    if (node0 + 1 < N_NODES) off[node0 + 1] = e0 + ex1;
    __syncthreads();
    hist[2 * t] = ex0;  // reuse as relative cursors
    hist[2 * t + 1] = ex1;
    __syncthreads();
    for (int e = e0 + t; e < e1; e += 256) {
        unsigned v = binned[e];
        int dl = v & (BK_NODES - 1);
        int p = atomicAdd(&hist[dl], 1);
        csr[e0 + p] = (int)(v >> BK_SHIFT);
    }
}

// ---------------- weights: W -> W^T bf16 ----------------

__global__ void wcast(const float* __restrict__ W1, const float* __restrict__ W2,
                      unsigned short* __restrict__ W1T, unsigned short* __restrict__ W2T) {
    int i = blockIdx.x * 256 + threadIdx.x;
    if (i >= 2 * 16384) return;
    const float* W = (i < 16384) ? W1 : W2;
    unsigned short* T = (i < 16384) ? W1T : W2T;
    int ii = i & 16383;
    int j = ii >> 7, k = ii & 127;  // T[j][k] = W[k][j]
    T[ii] = f2bf(W[k * 128 + j]);
}

// ---------------- fused GEMM: out = lrelu(A @ W + bias (+ res)) ----------------
template <bool A_F32, bool RES, bool WB16>
__global__ __launch_bounds__(256) void gemm_fused(
    const void* __restrict__ Av, const unsigned short* __restrict__ WT,
    const float* __restrict__ bias, const float* __restrict__ res,
    float* __restrict__ outF, unsigned short* __restrict__ outB) {
    __shared__ unsigned short wlds[128][136];  // +8 pad: 2-way bank alias only (free)
    const int tid = threadIdx.x;
#pragma unroll
    for (int it = 0; it < 8; ++it) {
        int idx = it * 256 + tid;
        int r = idx >> 4, c = (idx & 15) << 3;
        *reinterpret_cast<ush8*>(&wlds[r][c]) =
            *reinterpret_cast<const ush8*>(&WT[r * 128 + c]);
    }
    __syncthreads();

    const int lane = tid & 63, wave = tid >> 6;
    const int row0 = blockIdx.x * 64 + wave * 16;
    const int rl = lane & 15, kg = lane >> 4;
    int arow = row0 + rl;
    if (arow >= N_NODES) arow = N_NODES - 1;  // clamp (stores are guarded)

    bf8 af[4];
    if (A_F32) {
        const float* A = (const float*)Av;
#pragma unroll
        for (int kk = 0; kk < 4; ++kk) {
            const float* p = &A[arow * 128 + kk * 32 + kg * 8];
            float4 f0 = *reinterpret_cast<const float4*>(p);
            float4 f1 = *reinterpret_cast<const float4*>(p + 4);
            ush8 v;
            v[0] = f2bf(f0.x); v[1] = f2bf(f0.y); v[2] = f2bf(f0.z); v[3] = f2bf(f0.w);
            v[4] = f2bf(f1.x); v[5] = f2bf(f1.y); v[6] = f2bf(f1.z); v[7] = f2bf(f1.w);
            af[kk] = __builtin_bit_cast(bf8, v);
        }
    } else {
        const unsigned short* A = (const unsigned short*)Av;
#pragma unroll
        for (int kk = 0; kk < 4; ++kk)
            af[kk] = __builtin_bit_cast(
                bf8, *reinterpret_cast<const ush8*>(&A[arow * 128 + kk * 32 + kg * 8]));
    }

    f4 acc[8];
#pragma unroll
    for (int jt = 0; jt < 8; ++jt) acc[jt] = (f4)(0.0f);

#pragma unroll
    for (int jt = 0; jt < 8; ++jt) {
#pragma unroll
        for (int kk = 0; kk < 4; ++kk) {
            bf8 bfr = __builtin_bit_cast(
                bf8, *reinterpret_cast<const ush8*>(&wlds[jt * 16 + rl][kk * 32 + kg * 8]));
            acc[jt] = __builtin_amdgcn_mfma_f32_16x16x32_bf16(af[kk], bfr, acc[jt], 0, 0, 0);
        }
    }

#pragma unroll
    for (int jt = 0; jt < 8; ++jt) {
        int col = jt * 16 + rl;
        float bcol = bias[col];
#pragma unroll
        for (int i = 0; i < 4; ++i) {
            int r = row0 + kg * 4 + i;
            if (r < N_NODES) {
                float v = acc[jt][i] + bcol;
                if (RES) v += res[r * 128 + col];
                v = lrelu(v);
                outF[r * 128 + col] = v;
                if (WB16) outB[r * 128 + col] = f2bf(v);
            }
        }
    }
}

// ---------------- aggregation: m[dst] = bf16(mean_{src in N(dst)} h[src]) ----------------
__global__ __launch_bounds__(256) void agg_kernel(
    const unsigned short* __restrict__ h, const int* __restrict__ off,
    const int* __restrict__ csr, unsigned short* __restrict__ m) {
    int row = blockIdx.x * 4 + (threadIdx.x >> 6);
    if (row >= N_NODES) return;
    int lane = threadIdx.x & 63;
    int e0 = off[row], e1 = off[row + 1];
    const unsigned* hb = reinterpret_cast<const unsigned*>(h);  // [N][64] packed bf16x2
    float ax = 0.0f, ay = 0.0f;
    int e = e0;
    for (; e + 8 <= e1; e += 8) {
        int s[8];
#pragma unroll
        for (int k = 0; k < 8; ++k) s[k] = csr[e + k];
#pragma unroll
        for (int k = 0; k < 8; ++k) {
            unsigned u = hb[s[k] * 64 + lane];
            ax += __builtin_bit_cast(float, u << 16);
            ay += __builtin_bit_cast(float, u & 0xFFFF0000u);
        }
    }
    for (; e + 2 <= e1; e += 2) {
        unsigned u0 = hb[csr[e] * 64 + lane];
        unsigned u1 = hb[csr[e + 1] * 64 + lane];
        ax += __builtin_bit_cast(float, u0 << 16) + __builtin_bit_cast(float, u1 << 16);
        ay += __builtin_bit_cast(float, u0 & 0xFFFF0000u) +
              __builtin_bit_cast(float, u1 & 0xFFFF0000u);
    }
    if (e < e1) {
        unsigned u = hb[csr[e] * 64 + lane];
        ax += __builtin_bit_cast(float, u << 16);
        ay += __builtin_bit_cast(float, u & 0xFFFF0000u);
    }
    int d = e1 - e0;
    float inv = (d > 0) ? 1.0f / (float)d : 0.0f;
    unsigned pk = ((unsigned)f2bf(ay * inv) << 16) | (unsigned)f2bf(ax * inv);
    reinterpret_cast<unsigned*>(m)[row * 64 + lane] = pk;
}

// ---------------- launch ----------------

extern "C" void kernel_launch(void* const* d_in, const int* in_sizes, int n_in,
                              void* d_out, int out_size, void* d_ws, size_t ws_size,
                              hipStream_t stream) {
    const float* x  = (const float*)d_in[0];
    const float* W1 = (const float*)d_in[1];
    const float* b1 = (const float*)d_in[2];
    const float* W2 = (const float*)d_in[3];
    const float* b2 = (const float*)d_in[4];
    const int* esrc = (const int*)d_in[5];
    const int* edst = (const int*)d_in[6];
    float* out = (float*)d_out;

    char* ws = (char*)d_ws;
    size_t o = 0;
    auto alloc = [&](size_t b) {
        void* p = ws + o;
        o += (b + 511) & ~(size_t)511;
        return p;
    };
    int* bcnt = (int*)alloc(NBKT * 4);
    int* boff = (int*)alloc((NBKT + 1) * 4);
    int* bcur = (int*)alloc(NBKT * 4);
    int* off  = (int*)alloc(((size_t)N_NODES + 1) * 4);
    int* csr  = (int*)alloc((size_t)N_EDGES * 4);
    unsigned short* W1T = (unsigned short*)alloc(128 * 128 * 2);
    unsigned short* W2T = (unsigned short*)alloc(128 * 128 * 2);
    float* ha = (float*)alloc((size_t)N_NODES * 128 * 4);            // f32 h (residual)
    unsigned short* hB = (unsigned short*)alloc((size_t)N_NODES * 128 * 2);  // bf16 h (agg)
    unsigned short* m  = (unsigned short*)alloc((size_t)N_NODES * 128 * 2);
    unsigned* binned = (unsigned*)m;  // alias: binned only live before first agg

    hipMemsetAsync(bcnt, 0, NBKT * 4, stream);
    bucket_count<<<NBLK_EDGE, 256, 0, stream>>>(edst, bcnt);
    scan_buckets<<<1, 256, 0, stream>>>(bcnt, boff, bcur, off);
    bucket_scatter<<<NBLK_EDGE, 256, 0, stream>>>(esrc, edst, bcur, binned);
    bucket_place<<<NBKT, 256, 0, stream>>>(binned, boff, off, csr);

    wcast<<<(2 * 16384 + 255) / 256, 256, 0, stream>>>(W1, W2, W1T, W2T);

    const int GB = (N_NODES + 63) / 64;  // 1563
    // fc1: h0 = lrelu(x @ W1 + b1)  -> f32 ha + bf16 hB
    gemm_fused<true, false, true><<<GB, 256, 0, stream>>>(x, W1T, b1, nullptr, ha, hB);

    // iter 0: res=ha -> outF=out (+hB)
    agg_kernel<<<(N_NODES + 3) / 4, 256, 0, stream>>>(hB, off, csr, m);
    gemm_fused<false, true, true><<<GB, 256, 0, stream>>>(m, W2T, b2, ha, out, hB);
    // iter 1: res=out -> outF=ha (+hB)
    agg_kernel<<<(N_NODES + 3) / 4, 256, 0, stream>>>(hB, off, csr, m);
    gemm_fused<false, true, true><<<GB, 256, 0, stream>>>(m, W2T, b2, out, ha, hB);
    // iter 2 (final): res=ha -> outF=out (d_out), no bf16 store
    agg_kernel<<<(N_NODES + 3) / 4, 256, 0, stream>>>(hB, off, csr, m);
    gemm_fused<false, true, false><<<GB, 256, 0, stream>>>(m, W2T, b2, ha, out, nullptr);
}

// Round 4
// 477.976 us; speedup vs baseline: 1.4781x; 1.0204x over previous
//
#include <hip/hip_runtime.h>
#include <hip/hip_bf16.h>

#define N_NODES 100000
#define N_EDGES 1600000
// F == H == 128

#define BK_SHIFT 9
#define BK_NODES 512
#define NBKT 196              // ceil(N_NODES / 512)
#define EDGES_PER_BLK 8192
#define NBLK_EDGE ((N_EDGES + EDGES_PER_BLK - 1) / EDGES_PER_BLK)  // 196

typedef unsigned short ush8 __attribute__((ext_vector_type(8)));
typedef __bf16 bf8 __attribute__((ext_vector_type(8)));
typedef float f4 __attribute__((ext_vector_type(4)));

__device__ __forceinline__ float lrelu(float v) {
    return v >= 0.0f ? v : 0.01f * v;
}

// f32 -> bf16 (RNE), bit-pattern as ushort
__device__ __forceinline__ unsigned short f2bf(float f) {
    unsigned u = __builtin_bit_cast(unsigned, f);
    return (unsigned short)((u + 0x7FFFu + ((u >> 16) & 1u)) >> 16);
}

__device__ __forceinline__ float bfhi(unsigned u) {  // high bf16 -> f32
    return __builtin_bit_cast(float, u & 0xFFFF0000u);
}
__device__ __forceinline__ float bflo(unsigned u) {  // low bf16 -> f32
    return __builtin_bit_cast(float, u << 16);
}

// ---------------- CSR build (bucketed counting sort, dense writes) ----------------

__global__ __launch_bounds__(256) void bucket_count(const int* __restrict__ dst,
                                                    int* __restrict__ bcnt) {
    __shared__ int h[NBKT];
    int t = threadIdx.x;
    for (int i = t; i < NBKT; i += 256) h[i] = 0;
    __syncthreads();
    int base = blockIdx.x * EDGES_PER_BLK;
#pragma unroll 4
    for (int k = 0; k < EDGES_PER_BLK / 256; ++k) {
        int e = base + k * 256 + t;
        if (e < N_EDGES) atomicAdd(&h[dst[e] >> BK_SHIFT], 1);
    }
    __syncthreads();
    for (int i = t; i < NBKT; i += 256)
        if (h[i]) atomicAdd(&bcnt[i], h[i]);
}

// single block: exclusive scan of bucket counts -> boff/bcur; boff[NBKT]=E, off[N]=E
__global__ void scan_buckets(const int* __restrict__ bcnt, int* __restrict__ boff,
                             int* __restrict__ bcur, int* __restrict__ off) {
    __shared__ int lds[256];
    int t = threadIdx.x;
    int v = (t < NBKT) ? bcnt[t] : 0;
    lds[t] = v;
    __syncthreads();
    for (int d = 1; d < 256; d <<= 1) {
        int a = (t >= d) ? lds[t - d] : 0;
        __syncthreads();
        lds[t] += a;
        __syncthreads();
    }
    if (t < NBKT) {
        int excl = lds[t] - v;
        boff[t] = excl;
        bcur[t] = excl;
    }
    if (t == 0) {
        boff[NBKT] = N_EDGES;
        off[N_NODES] = N_EDGES;
    }
}

// scatter edges into bucket-grouped array, packed (src<<9)|dst_local
__global__ __launch_bounds__(256) void bucket_scatter(const int* __restrict__ src,
                                                      const int* __restrict__ dst,
                                                      int* __restrict__ bcur,
                                                      unsigned* __restrict__ binned) {
    __shared__ int h[NBKT];
    __shared__ int bbase[NBKT];
    int t = threadIdx.x;
    for (int i = t; i < NBKT; i += 256) h[i] = 0;
    __syncthreads();
    int base = blockIdx.x * EDGES_PER_BLK;
#pragma unroll 4
    for (int k = 0; k < EDGES_PER_BLK / 256; ++k) {
        int e = base + k * 256 + t;
        if (e < N_EDGES) atomicAdd(&h[dst[e] >> BK_SHIFT], 1);
    }
    __syncthreads();
    for (int i = t; i < NBKT; i += 256) {
        int c = h[i];
        bbase[i] = c ? atomicAdd(&bcur[i], c) : 0;
        h[i] = 0;  // reuse as local cursor
    }
    __syncthreads();
#pragma unroll 4
    for (int k = 0; k < EDGES_PER_BLK / 256; ++k) {
        int e = base + k * 256 + t;
        if (e < N_EDGES) {
            int d = dst[e], s = src[e];
            int b = d >> BK_SHIFT;
            int p = bbase[b] + atomicAdd(&h[b], 1);
            binned[p] = ((unsigned)s << BK_SHIFT) | (unsigned)(d & (BK_NODES - 1));
        }
    }
}

// one block per bucket: local histogram -> scan -> write off[] -> place csr
__global__ __launch_bounds__(256) void bucket_place(const unsigned* __restrict__ binned,
                                                    const int* __restrict__ boff,
                                                    int* __restrict__ off,
                                                    int* __restrict__ csr) {
    __shared__ int hist[BK_NODES];
    __shared__ int pair[256];
    int b = blockIdx.x, t = threadIdx.x;
    int e0 = boff[b], e1 = boff[b + 1];
    hist[t] = 0;
    hist[t + 256] = 0;
    __syncthreads();
    for (int e = e0 + t; e < e1; e += 256)
        atomicAdd(&hist[binned[e] & (BK_NODES - 1)], 1);
    __syncthreads();
    int h0 = hist[2 * t], h1 = hist[2 * t + 1];
    pair[t] = h0 + h1;
    __syncthreads();
    for (int d = 1; d < 256; d <<= 1) {
        int a = (t >= d) ? pair[t - d] : 0;
        __syncthreads();
        pair[t] += a;
        __syncthreads();
    }
    int ep = pair[t] - (h0 + h1);  // exclusive prefix of this pair
    int ex0 = ep, ex1 = ep + h0;
    int node0 = b * BK_NODES + 2 * t;
    if (node0 < N_NODES) off[node0] = e0 + ex0;
    if (node0 + 1 < N_NODES) off[node0 + 1] = e0 + ex1;
    __syncthreads();
    hist[2 * t] = ex0;  // reuse as relative cursors
    hist[2 * t + 1] = ex1;
    __syncthreads();
    for (int e = e0 + t; e < e1; e += 256) {
        unsigned v = binned[e];
        int dl = v & (BK_NODES - 1);
        int p = atomicAdd(&hist[dl], 1);
        csr[e0 + p] = (int)(v >> BK_SHIFT);
    }
}

// ---------------- weights: W -> W^T bf16 ----------------

__global__ void wcast(const float* __restrict__ W1, const float* __restrict__ W2,
                      unsigned short* __restrict__ W1T, unsigned short* __restrict__ W2T) {
    int i = blockIdx.x * 256 + threadIdx.x;
    if (i >= 2 * 16384) return;
    const float* W = (i < 16384) ? W1 : W2;
    unsigned short* T = (i < 16384) ? W1T : W2T;
    int ii = i & 16383;
    int j = ii >> 7, k = ii & 127;  // T[j][k] = W[k][j]
    T[ii] = f2bf(W[k * 128 + j]);
}

// ---------------- fused GEMM: out = lrelu(A @ W + bias (+ res)) ----------------
// A: [N][128] (f32 or bf16), WT: [128][128] bf16 as W^T. Residual (bf16) added
// via identity-MFMA (vectorized loads, no scalar 2B reads).
template <bool A_F32, bool RES, bool WF32, bool WB16>
__global__ __launch_bounds__(256) void gemm_fused(
    const void* __restrict__ Av, const unsigned short* __restrict__ WT,
    const float* __restrict__ bias, const unsigned short* __restrict__ resB,
    float* __restrict__ outF, unsigned short* __restrict__ outB) {
    __shared__ unsigned short wlds[128][136];  // +8 pad: 2-way bank alias only (free)
    const int tid = threadIdx.x;
#pragma unroll
    for (int it = 0; it < 8; ++it) {
        int idx = it * 256 + tid;
        int r = idx >> 4, c = (idx & 15) << 3;
        *reinterpret_cast<ush8*>(&wlds[r][c]) =
            *reinterpret_cast<const ush8*>(&WT[r * 128 + c]);
    }

    const int lane = tid & 63, wave = tid >> 6;
    const int row0 = blockIdx.x * 64 + wave * 16;
    const int rl = lane & 15, kg = lane >> 4;
    int arow = row0 + rl;
    if (arow >= N_NODES) arow = N_NODES - 1;  // clamp (stores are guarded)

    bf8 af[4];
    if (A_F32) {
        const float* A = (const float*)Av;
#pragma unroll
        for (int kk = 0; kk < 4; ++kk) {
            const float* p = &A[arow * 128 + kk * 32 + kg * 8];
            float4 f0 = *reinterpret_cast<const float4*>(p);
            float4 f1 = *reinterpret_cast<const float4*>(p + 4);
            ush8 v;
            v[0] = f2bf(f0.x); v[1] = f2bf(f0.y); v[2] = f2bf(f0.z); v[3] = f2bf(f0.w);
            v[4] = f2bf(f1.x); v[5] = f2bf(f1.y); v[6] = f2bf(f1.z); v[7] = f2bf(f1.w);
            af[kk] = __builtin_bit_cast(bf8, v);
        }
    } else {
        const unsigned short* A = (const unsigned short*)Av;
#pragma unroll
        for (int kk = 0; kk < 4; ++kk)
            af[kk] = __builtin_bit_cast(
                bf8, *reinterpret_cast<const ush8*>(&A[arow * 128 + kk * 32 + kg * 8]));
    }

    f4 acc[8];
#pragma unroll
    for (int jt = 0; jt < 8; ++jt) acc[jt] = (f4)(0.0f);

    if (RES) {
        // identity B fragment: B[k][col] = (k == col), k = kg*8+j, col = rl
        ush8 bi;
#pragma unroll
        for (int j = 0; j < 8; ++j)
            bi[j] = (kg * 8 + j == rl) ? (unsigned short)0x3F80 : (unsigned short)0;
        bf8 bfi = __builtin_bit_cast(bf8, bi);
#pragma unroll
        for (int jt = 0; jt < 8; ++jt) {
            // A[row][k] = res[row][jt*16 + k] for k<16 (kg 2,3 re-load kg 0,1's
            // bytes; killed by zero B rows). acc[jt] += res[:, jt*16..+16] @ I
            bf8 ra = __builtin_bit_cast(
                bf8, *reinterpret_cast<const ush8*>(
                         &resB[arow * 128 + jt * 16 + (kg & 1) * 8]));
            acc[jt] = __builtin_amdgcn_mfma_f32_16x16x32_bf16(ra, bfi, acc[jt], 0, 0, 0);
        }
    }

    __syncthreads();

#pragma unroll
    for (int jt = 0; jt < 8; ++jt) {
#pragma unroll
        for (int kk = 0; kk < 4; ++kk) {
            bf8 bfr = __builtin_bit_cast(
                bf8, *reinterpret_cast<const ush8*>(&wlds[jt * 16 + rl][kk * 32 + kg * 8]));
            acc[jt] = __builtin_amdgcn_mfma_f32_16x16x32_bf16(af[kk], bfr, acc[jt], 0, 0, 0);
        }
    }

#pragma unroll
    for (int jt = 0; jt < 8; ++jt) {
        int col = jt * 16 + rl;
        float bcol = bias[col];
#pragma unroll
        for (int i = 0; i < 4; ++i) {
            int r = row0 + kg * 4 + i;
            if (r < N_NODES) {
                float v = acc[jt][i] + bcol;
                v = lrelu(v);
                if (WF32) outF[r * 128 + col] = v;
                if (WB16) outB[r * 128 + col] = f2bf(v);
            }
        }
    }
}

// ---------------- aggregation: m[dst] = bf16(mean_{src in N(dst)} h[src]) ----------------
// One wave per dst row. Wave halves process even/odd edges; lane loads uint2
// (4 bf16 = cols 4*hl..4*hl+3); halves combined via shfl_xor(32) at the end.
__global__ __launch_bounds__(256) void agg_kernel(
    const unsigned short* __restrict__ h, const int* __restrict__ off,
    const int* __restrict__ csr, unsigned short* __restrict__ m) {
    int row = blockIdx.x * 4 + (threadIdx.x >> 6);
    if (row >= N_NODES) return;
    int lane = threadIdx.x & 63;
    int half = lane >> 5, hl = lane & 31;
    int e0 = off[row], e1 = off[row + 1];
    const uint2* hb = reinterpret_cast<const uint2*>(h);  // [N][32] of 8B
    float a0 = 0.f, a1 = 0.f, a2 = 0.f, a3 = 0.f;
    int e = e0 + half;
    for (; e + 8 <= e1; e += 8) {  // 4 edges per half per iter (8 total in wave)
        int s0 = csr[e], s1 = csr[e + 2], s2 = csr[e + 4], s3 = csr[e + 6];
        uint2 v0 = hb[s0 * 32 + hl];
        uint2 v1 = hb[s1 * 32 + hl];
        uint2 v2 = hb[s2 * 32 + hl];
        uint2 v3 = hb[s3 * 32 + hl];
        a0 += bflo(v0.x) + bflo(v1.x) + bflo(v2.x) + bflo(v3.x);
        a1 += bfhi(v0.x) + bfhi(v1.x) + bfhi(v2.x) + bfhi(v3.x);
        a2 += bflo(v0.y) + bflo(v1.y) + bflo(v2.y) + bflo(v3.y);
        a3 += bfhi(v0.y) + bfhi(v1.y) + bfhi(v2.y) + bfhi(v3.y);
    }
    for (; e < e1; e += 2) {
        uint2 v = hb[csr[e] * 32 + hl];
        a0 += bflo(v.x);
        a1 += bfhi(v.x);
        a2 += bflo(v.y);
        a3 += bfhi(v.y);
    }
    a0 += __shfl_xor(a0, 32);
    a1 += __shfl_xor(a1, 32);
    a2 += __shfl_xor(a2, 32);
    a3 += __shfl_xor(a3, 32);
    int d = e1 - e0;
    float inv = (d > 0) ? 1.0f / (float)d : 0.0f;
    if (half == 0) {
        uint2 pk;
        pk.x = ((unsigned)f2bf(a1 * inv) << 16) | (unsigned)f2bf(a0 * inv);
        pk.y = ((unsigned)f2bf(a3 * inv) << 16) | (unsigned)f2bf(a2 * inv);
        reinterpret_cast<uint2*>(m)[row * 32 + hl] = pk;
    }
}

// ---------------- launch ----------------

extern "C" void kernel_launch(void* const* d_in, const int* in_sizes, int n_in,
                              void* d_out, int out_size, void* d_ws, size_t ws_size,
                              hipStream_t stream) {
    const float* x  = (const float*)d_in[0];
    const float* W1 = (const float*)d_in[1];
    const float* b1 = (const float*)d_in[2];
    const float* W2 = (const float*)d_in[3];
    const float* b2 = (const float*)d_in[4];
    const int* esrc = (const int*)d_in[5];
    const int* edst = (const int*)d_in[6];
    float* out = (float*)d_out;

    char* ws = (char*)d_ws;
    size_t o = 0;
    auto alloc = [&](size_t b) {
        void* p = ws + o;
        o += (b + 511) & ~(size_t)511;
        return p;
    };
    int* bcnt = (int*)alloc(NBKT * 4);
    int* boff = (int*)alloc((NBKT + 1) * 4);
    int* bcur = (int*)alloc(NBKT * 4);
    int* off  = (int*)alloc(((size_t)N_NODES + 1) * 4);
    int* csr  = (int*)alloc((size_t)N_EDGES * 4);
    unsigned short* W1T = (unsigned short*)alloc(128 * 128 * 2);
    unsigned short* W2T = (unsigned short*)alloc(128 * 128 * 2);
    unsigned short* hB = (unsigned short*)alloc((size_t)N_NODES * 128 * 2);  // bf16 h
    unsigned short* m  = (unsigned short*)alloc((size_t)N_NODES * 128 * 2);
    unsigned* binned = (unsigned*)m;  // alias: binned only live before first agg

    hipMemsetAsync(bcnt, 0, NBKT * 4, stream);
    bucket_count<<<NBLK_EDGE, 256, 0, stream>>>(edst, bcnt);
    scan_buckets<<<1, 256, 0, stream>>>(bcnt, boff, bcur, off);
    bucket_scatter<<<NBLK_EDGE, 256, 0, stream>>>(esrc, edst, bcur, binned);
    bucket_place<<<NBKT, 256, 0, stream>>>(binned, boff, off, csr);

    wcast<<<(2 * 16384 + 255) / 256, 256, 0, stream>>>(W1, W2, W1T, W2T);

    const int GB = (N_NODES + 63) / 64;  // 1563
    // fc1: hB = bf16(lrelu(x @ W1 + b1))
    gemm_fused<true, false, false, true><<<GB, 256, 0, stream>>>(
        x, W1T, b1, nullptr, nullptr, hB);

    // iters 0,1: hB = bf16(lrelu(m @ W2 + b2 + hB))   (in-place, safe per-wave)
    for (int it = 0; it < 2; ++it) {
        agg_kernel<<<(N_NODES + 3) / 4, 256, 0, stream>>>(hB, off, csr, m);
        gemm_fused<false, true, false, true><<<GB, 256, 0, stream>>>(
            m, W2T, b2, hB, nullptr, hB);
    }
    // final iter: out(f32) = lrelu(m @ W2 + b2 + hB)
    agg_kernel<<<(N_NODES + 3) / 4, 256, 0, stream>>>(hB, off, csr, m);
    gemm_fused<false, true, true, false><<<GB, 256, 0, stream>>>(
        m, W2T, b2, hB, out, nullptr);
}

// Round 6
// 398.378 us; speedup vs baseline: 1.7734x; 1.1998x over previous
//
#include <hip/hip_runtime.h>
#include <hip/hip_bf16.h>

#define N_NODES 100000
#define N_EDGES 1600000
// F == H == 128

#define BK_SHIFT 9
#define BK_NODES 512
#define NBKT 196              // ceil(N_NODES / 512)
#define EDGES_PER_BLK 8192
#define NBLK_EDGE ((N_EDGES + EDGES_PER_BLK - 1) / EDGES_PER_BLK)  // 196

typedef unsigned short ush8 __attribute__((ext_vector_type(8)));
typedef __bf16 bf8 __attribute__((ext_vector_type(8)));
typedef float f4 __attribute__((ext_vector_type(4)));

__device__ __forceinline__ float lrelu(float v) {
    return v >= 0.0f ? v : 0.01f * v;
}

// f32 -> bf16 (RNE)
__device__ __forceinline__ unsigned short f2bf(float f) {
    unsigned u = __builtin_bit_cast(unsigned, f);
    return (unsigned short)((u + 0x7FFFu + ((u >> 16) & 1u)) >> 16);
}
__device__ __forceinline__ float bfs(unsigned short u) {  // bf16 -> f32
    return __builtin_bit_cast(float, (unsigned)u << 16);
}
__device__ __forceinline__ float bfhi(unsigned u) {
    return __builtin_bit_cast(float, u & 0xFFFF0000u);
}
__device__ __forceinline__ float bflo(unsigned u) {
    return __builtin_bit_cast(float, u << 16);
}

// ---------------- CSR build (bucketed counting sort, dense writes) ----------------

__global__ __launch_bounds__(256) void bucket_count(const int* __restrict__ dst,
                                                    int* __restrict__ bcnt) {
    __shared__ int h[NBKT];
    int t = threadIdx.x;
    for (int i = t; i < NBKT; i += 256) h[i] = 0;
    __syncthreads();
    int base = blockIdx.x * EDGES_PER_BLK;
#pragma unroll 4
    for (int k = 0; k < EDGES_PER_BLK / 256; ++k) {
        int e = base + k * 256 + t;
        if (e < N_EDGES) atomicAdd(&h[dst[e] >> BK_SHIFT], 1);
    }
    __syncthreads();
    for (int i = t; i < NBKT; i += 256)
        if (h[i]) atomicAdd(&bcnt[i], h[i]);
}

__global__ void scan_buckets(const int* __restrict__ bcnt, int* __restrict__ boff,
                             int* __restrict__ bcur, int* __restrict__ off) {
    __shared__ int lds[256];
    int t = threadIdx.x;
    int v = (t < NBKT) ? bcnt[t] : 0;
    lds[t] = v;
    __syncthreads();
    for (int d = 1; d < 256; d <<= 1) {
        int a = (t >= d) ? lds[t - d] : 0;
        __syncthreads();
        lds[t] += a;
        __syncthreads();
    }
    if (t < NBKT) {
        int excl = lds[t] - v;
        boff[t] = excl;
        bcur[t] = excl;
    }
    if (t == 0) {
        boff[NBKT] = N_EDGES;
        off[N_NODES] = N_EDGES;
    }
}

__global__ __launch_bounds__(256) void bucket_scatter(const int* __restrict__ src,
                                                      const int* __restrict__ dst,
                                                      int* __restrict__ bcur,
                                                      unsigned* __restrict__ binned) {
    __shared__ int h[NBKT];
    __shared__ int bbase[NBKT];
    int t = threadIdx.x;
    for (int i = t; i < NBKT; i += 256) h[i] = 0;
    __syncthreads();
    int base = blockIdx.x * EDGES_PER_BLK;
#pragma unroll 4
    for (int k = 0; k < EDGES_PER_BLK / 256; ++k) {
        int e = base + k * 256 + t;
        if (e < N_EDGES) atomicAdd(&h[dst[e] >> BK_SHIFT], 1);
    }
    __syncthreads();
    for (int i = t; i < NBKT; i += 256) {
        int c = h[i];
        bbase[i] = c ? atomicAdd(&bcur[i], c) : 0;
        h[i] = 0;  // reuse as local cursor
    }
    __syncthreads();
#pragma unroll 4
    for (int k = 0; k < EDGES_PER_BLK / 256; ++k) {
        int e = base + k * 256 + t;
        if (e < N_EDGES) {
            int d = dst[e], s = src[e];
            int b = d >> BK_SHIFT;
            int p = bbase[b] + atomicAdd(&h[b], 1);
            binned[p] = ((unsigned)s << BK_SHIFT) | (unsigned)(d & (BK_NODES - 1));
        }
    }
}

__global__ __launch_bounds__(256) void bucket_place(const unsigned* __restrict__ binned,
                                                    const int* __restrict__ boff,
                                                    int* __restrict__ off,
                                                    int* __restrict__ csr) {
    __shared__ int hist[BK_NODES];
    __shared__ int pair[256];
    int b = blockIdx.x, t = threadIdx.x;
    int e0 = boff[b], e1 = boff[b + 1];
    hist[t] = 0;
    hist[t + 256] = 0;
    __syncthreads();
    for (int e = e0 + t; e < e1; e += 256)
        atomicAdd(&hist[binned[e] & (BK_NODES - 1)], 1);
    __syncthreads();
    int h0 = hist[2 * t], h1 = hist[2 * t + 1];
    pair[t] = h0 + h1;
    __syncthreads();
    for (int d = 1; d < 256; d <<= 1) {
        int a = (t >= d) ? pair[t - d] : 0;
        __syncthreads();
        pair[t] += a;
        __syncthreads();
    }
    int ep = pair[t] - (h0 + h1);
    int ex0 = ep, ex1 = ep + h0;
    int node0 = b * BK_NODES + 2 * t;
    if (node0 < N_NODES) off[node0] = e0 + ex0;
    if (node0 + 1 < N_NODES) off[node0 + 1] = e0 + ex1;
    __syncthreads();
    hist[2 * t] = ex0;
    hist[2 * t + 1] = ex1;
    __syncthreads();
    for (int e = e0 + t; e < e1; e += 256) {
        unsigned v = binned[e];
        int dl = v & (BK_NODES - 1);
        int p = atomicAdd(&hist[dl], 1);
        csr[e0 + p] = (int)(v >> BK_SHIFT);
    }
}

// ---------------- weights ----------------
// W1T: true-k layout   W1T[col][k]    = W1[k][col]
// W2T: permuted-k      W2T[col][q]    = W2[k(q)][col],  k(q) = 16*(q&7) + (q>>3)
__global__ void wcast(const float* __restrict__ W1, const float* __restrict__ W2,
                      unsigned short* __restrict__ W1T, unsigned short* __restrict__ W2T) {
    int i = blockIdx.x * 256 + threadIdx.x;
    if (i >= 2 * 16384) return;
    int ii = i & 16383;
    int col = ii >> 7, q = ii & 127;
    if (i < 16384) {
        W1T[ii] = f2bf(W1[q * 128 + col]);
    } else {
        int k = 16 * (q & 7) + (q >> 3);
        W2T[ii] = f2bf(W2[k * 128 + col]);
    }
}

// ---------------- fused GEMM ----------------
// out = lrelu(A @ W + bias (+ res)).
// Permuted column layout: position p = (c&15)*8 + (c>>4). Lane (kg,rl), row
// kg*4+i holds acc[j][i] = col 16j+rl = positions rl*8+j -> ONE dwordx4 store
// per row. Residual read is position-matched (same 16B addr as the store).
// FINAL: write f32 in TRUE layout (scatter) to d_out.
template <bool A_F32, bool RES, bool FINAL>
__global__ __launch_bounds__(256) void gemm_fused(
    const void* __restrict__ Av, const unsigned short* __restrict__ WT,
    const float* __restrict__ bias, const unsigned short* __restrict__ resB,
    float* __restrict__ outF, unsigned short* __restrict__ outB) {
    __shared__ unsigned short wlds[128][136];  // +8 pad
    const int tid = threadIdx.x;
#pragma unroll
    for (int it = 0; it < 8; ++it) {
        int idx = it * 256 + tid;
        int r = idx >> 4, c = (idx & 15) << 3;
        *reinterpret_cast<ush8*>(&wlds[r][c]) =
            *reinterpret_cast<const ush8*>(&WT[r * 128 + c]);
    }

    const int lane = tid & 63, wave = tid >> 6;
    const int row0 = blockIdx.x * 64 + wave * 16;
    const int rl = lane & 15, kg = lane >> 4;
    int arow = row0 + rl;
    if (arow >= N_NODES) arow = N_NODES - 1;  // clamp (stores are guarded)

    bf8 af[4];
    if (A_F32) {
        const float* A = (const float*)Av;
#pragma unroll
        for (int kk = 0; kk < 4; ++kk) {
            const float* p = &A[arow * 128 + kk * 32 + kg * 8];
            float4 f0 = *reinterpret_cast<const float4*>(p);
            float4 f1 = *reinterpret_cast<const float4*>(p + 4);
            ush8 v;
            v[0] = f2bf(f0.x); v[1] = f2bf(f0.y); v[2] = f2bf(f0.z); v[3] = f2bf(f0.w);
            v[4] = f2bf(f1.x); v[5] = f2bf(f1.y); v[6] = f2bf(f1.z); v[7] = f2bf(f1.w);
            af[kk] = __builtin_bit_cast(bf8, v);
        }
    } else {
        const unsigned short* A = (const unsigned short*)Av;
#pragma unroll
        for (int kk = 0; kk < 4; ++kk)
            af[kk] = __builtin_bit_cast(
                bf8, *reinterpret_cast<const ush8*>(&A[arow * 128 + kk * 32 + kg * 8]));
    }

    __syncthreads();

    f4 acc[8];
#pragma unroll
    for (int jt = 0; jt < 8; ++jt) acc[jt] = (f4)(0.0f);

#pragma unroll
    for (int jt = 0; jt < 8; ++jt) {
#pragma unroll
        for (int kk = 0; kk < 4; ++kk) {
            bf8 bfr = __builtin_bit_cast(
                bf8, *reinterpret_cast<const ush8*>(&wlds[jt * 16 + rl][kk * 32 + kg * 8]));
            acc[jt] = __builtin_amdgcn_mfma_f32_16x16x32_bf16(af[kk], bfr, acc[jt], 0, 0, 0);
        }
    }

    float bb[8];
#pragma unroll
    for (int j = 0; j < 8; ++j) bb[j] = bias[j * 16 + rl];

#pragma unroll
    for (int i = 0; i < 4; ++i) {
        int r = row0 + kg * 4 + i;
        int rc = (r < N_NODES) ? r : N_NODES - 1;
        ush8 rv;
        if (RES)
            rv = *reinterpret_cast<const ush8*>(&resB[rc * 128 + rl * 8]);
        float v[8];
#pragma unroll
        for (int j = 0; j < 8; ++j) {
            float t = acc[j][i] + bb[j];
            if (RES) t += bfs(rv[j]);
            v[j] = lrelu(t);
        }
        if (FINAL) {
            if (r < N_NODES) {
#pragma unroll
                for (int j = 0; j < 8; ++j) outF[r * 128 + j * 16 + rl] = v[j];
            }
        } else {
            ush8 sv;
#pragma unroll
            for (int j = 0; j < 8; ++j) sv[j] = f2bf(v[j]);
            if (r < N_NODES)
                *reinterpret_cast<ush8*>(&outB[r * 128 + rl * 8]) = sv;
        }
    }
}

// ---------------- aggregation: m[dst] = bf16(mean_{src} h[src]) ----------------
// One wave per dst row; lane owns positions 2*lane, 2*lane+1 (one packed u32).
// Layout-agnostic (elementwise over columns).
__global__ __launch_bounds__(256) void agg_kernel(
    const unsigned short* __restrict__ h, const int* __restrict__ off,
    const int* __restrict__ csr, unsigned short* __restrict__ m) {
    int row = blockIdx.x * 4 + (threadIdx.x >> 6);
    if (row >= N_NODES) return;
    int lane = threadIdx.x & 63;
    int e0 = off[row], e1 = off[row + 1];
    const unsigned* hb = reinterpret_cast<const unsigned*>(h);  // [N][64] bf16x2
    float ax = 0.0f, ay = 0.0f;
    int e = e0;
    for (; e + 16 <= e1; e += 16) {  // deep window: 16 index loads up front
        int s[16];
#pragma unroll
        for (int k = 0; k < 16; ++k) s[k] = csr[e + k];
#pragma unroll
        for (int k = 0; k < 16; ++k) {
            unsigned u = hb[s[k] * 64 + lane];
            ax += __builtin_bit_cast(float, u << 16);
            ay += __builtin_bit_cast(float, u & 0xFFFF0000u);
        }
    }
    for (; e + 8 <= e1; e += 8) {
        int s[8];
#pragma unroll
        for (int k = 0; k < 8; ++k) s[k] = csr[e + k];
#pragma unroll
        for (int k = 0; k < 8; ++k) {
            unsigned u = hb[s[k] * 64 + lane];
            ax += __builtin_bit_cast(float, u << 16);
            ay += __builtin_bit_cast(float, u & 0xFFFF0000u);
        }
    }
    for (; e + 2 <= e1; e += 2) {
        unsigned u0 = hb[csr[e] * 64 + lane];
        unsigned u1 = hb[csr[e + 1] * 64 + lane];
        ax += __builtin_bit_cast(float, u0 << 16) + __builtin_bit_cast(float, u1 << 16);
        ay += __builtin_bit_cast(float, u0 & 0xFFFF0000u) +
              __builtin_bit_cast(float, u1 & 0xFFFF0000u);
    }
    if (e < e1) {
        unsigned u = hb[csr[e] * 64 + lane];
        ax += __builtin_bit_cast(float, u << 16);
        ay += __builtin_bit_cast(float, u & 0xFFFF0000u);
    }
    int d = e1 - e0;
    float inv = (d > 0) ? 1.0f / (float)d : 0.0f;
    unsigned pk = ((unsigned)f2bf(ay * inv) << 16) | (unsigned)f2bf(ax * inv);
    reinterpret_cast<unsigned*>(m)[row * 64 + lane] = pk;
}

// ---------------- launch ----------------

extern "C" void kernel_launch(void* const* d_in, const int* in_sizes, int n_in,
                              void* d_out, int out_size, void* d_ws, size_t ws_size,
                              hipStream_t stream) {
    const float* x  = (const float*)d_in[0];
    const float* W1 = (const float*)d_in[1];
    const float* b1 = (const float*)d_in[2];
    const float* W2 = (const float*)d_in[3];
    const float* b2 = (const float*)d_in[4];
    const int* esrc = (const int*)d_in[5];
    const int* edst = (const int*)d_in[6];
    float* out = (float*)d_out;

    char* ws = (char*)d_ws;
    size_t o = 0;
    auto alloc = [&](size_t b) {
        void* p = ws + o;
        o += (b + 511) & ~(size_t)511;
        return p;
    };
    int* bcnt = (int*)alloc(NBKT * 4);
    int* boff = (int*)alloc((NBKT + 1) * 4);
    int* bcur = (int*)alloc(NBKT * 4);
    int* off  = (int*)alloc(((size_t)N_NODES + 1) * 4);
    int* csr  = (int*)alloc((size_t)N_EDGES * 4);
    unsigned short* W1T = (unsigned short*)alloc(128 * 128 * 2);
    unsigned short* W2T = (unsigned short*)alloc(128 * 128 * 2);
    unsigned short* hB = (unsigned short*)alloc((size_t)N_NODES * 128 * 2);  // bf16 h (permuted cols)
    unsigned short* m  = (unsigned short*)alloc((size_t)N_NODES * 128 * 2);
    unsigned* binned = (unsigned*)m;  // alias: binned only live before first agg

    hipMemsetAsync(bcnt, 0, NBKT * 4, stream);
    bucket_count<<<NBLK_EDGE, 256, 0, stream>>>(edst, bcnt);
    scan_buckets<<<1, 256, 0, stream>>>(bcnt, boff, bcur, off);
    bucket_scatter<<<NBLK_EDGE, 256, 0, stream>>>(esrc, edst, bcur, binned);
    bucket_place<<<NBKT, 256, 0, stream>>>(binned, boff, off, csr);

    wcast<<<(2 * 16384 + 255) / 256, 256, 0, stream>>>(W1, W2, W1T, W2T);

    const int GB = (N_NODES + 63) / 64;  // 1563
    // fc1: hB = bf16(lrelu(x @ W1 + b1)), permuted cols
    gemm_fused<true, false, false><<<GB, 256, 0, stream>>>(
        x, W1T, b1, nullptr, nullptr, hB);

    // iters 0,1: hB = bf16(lrelu(m @ W2 + b2 + hB))   (in-place, per-lane safe)
    for (int it = 0; it < 2; ++it) {
        agg_kernel<<<(N_NODES + 3) / 4, 256, 0, stream>>>(hB, off, csr, m);
        gemm_fused<false, true, false><<<GB, 256, 0, stream>>>(
            m, W2T, b2, hB, nullptr, hB);
    }
    // final iter: out(f32, true layout) = lrelu(m @ W2 + b2 + hB)
    agg_kernel<<<(N_NODES + 3) / 4, 256, 0, stream>>>(hB, off, csr, m);
    gemm_fused<false, true, true><<<GB, 256, 0, stream>>>(
        m, W2T, b2, hB, out, nullptr);
}